// Round 16
// baseline (142.655 us; speedup 1.0000x reference)
//
#include <hip/hip_runtime.h>
#include <hip/hip_bf16.h>

#define SROWS 16384
#define DIMK  4096
#define NE    64
#define BM    16                 // rows per block
#define NBLK  (SROWS/BM)         // 1024 blocks, 1/CU resident -> 4 generations
#define NSTEP 8                  // per step: 16 rows x 512 f32 (2 KB/row contiguous)
#define WSPLIT_SHORTS 262144     // shorts per (hi|lo) plane of pre-split W
#define WSOFF_F 262144           // f32 offset of partials region (skip 1 MB W-split)
#define WSOFF2  (WSOFF_F + NBLK*64)
#define LDS_BYTES 98304          // 2 x 32 KB x-buffers (+pad) -> forces 1 block/CU

typedef __attribute__((ext_vector_type(8))) short short8;
typedef __attribute__((ext_vector_type(4))) float f32x4;

// split 8 f32 -> 8 hi bf16 + 8 lo bf16 via HW cvt (RNE); f ~= hi + lo
__device__ __forceinline__ void split8(const float4 a, const float4 c, short8& hi, short8& lo) {
    float f[8] = {a.x, a.y, a.z, a.w, c.x, c.y, c.z, c.w};
    #pragma unroll
    for (int i = 0; i < 8; ++i) {
        unsigned short h = __bfloat16_as_ushort(__float2bfloat16(f[i]));
        float hf = __uint_as_float((unsigned)h << 16);
        unsigned short l = __bfloat16_as_ushort(__float2bfloat16(f[i] - hf));
        hi[i] = (short)h;
        lo[i] = (short)l;
    }
}

// pre-pass: split W into bf16 hi/lo planes in B-fragment order [k/8][e][8]
__global__ void w_split(const float* __restrict__ W, unsigned short* __restrict__ wsp)
{
    const int idx   = blockIdx.x * 256 + threadIdx.x;   // 0..32767
    const int kslot = idx & 511;
    const int e     = idx >> 9;
    const float* p = W + (size_t)e * DIMK + kslot * 8;
    float4 va = *reinterpret_cast<const float4*>(p);
    float4 vb = *reinterpret_cast<const float4*>(p + 4);
    short8 hi, lo;
    split8(va, vb, hi, lo);
    *reinterpret_cast<short8*>(wsp + (size_t)(kslot * 64 + e) * 8)                 = hi;
    *reinterpret_cast<short8*>(wsp + WSPLIT_SHORTS + (size_t)(kslot * 64 + e) * 8) = lo;
}

// async global -> LDS, 16B per lane (DMA; dst = wave-uniform base + lane*16)
__device__ __forceinline__ void gl_lds16(const void* g, void* l) {
    __builtin_amdgcn_global_load_lds(
        (const __attribute__((address_space(1))) void*)g,
        (__attribute__((address_space(3))) void*)l, 16, 0, 0);
}

__global__ __launch_bounds__(1024, 4) void gate_main(
    const float* __restrict__ x, const unsigned short* __restrict__ wsp,
    const float* __restrict__ b, float* __restrict__ out, float* __restrict__ ws)
{
    extern __shared__ __align__(16) char smem[];
    // x double buffer: buf s at smem + s*32768, layout [16 rows][2048 B], XOR-swizzled.
    //   Wave w stages ONLY row w: 2 KB contiguous per step -> block walks its 256 KB
    //   tile in address order; 256 resident blocks -> 4096 chip-wide DRAM streams.
    // epilogue alias: part[15*1024 f32] @0 | Lb[64*17 f32] @61440 | red[2048 f32] @65792

    const int tid  = threadIdx.x;
    const int lane = tid & 63;
    const int wid  = __builtin_amdgcn_readfirstlane(tid >> 6);  // 0..15 (k-split 16-way)
    const int row0 = blockIdx.x * BM;

    // staging sources: wave wid's row, granule pre-XOR-swizzled within 128 B windows
    const float* xs0 = x + (size_t)(row0 + wid) * DIMK + (lane ^ (wid & 7)) * 4;
    const float* xs1 = xs0 + 256;     // +64 granules

    auto STAGE = [&](int st, int bsel) {
        char* xb = smem + bsel * 32768 + wid * 2048;
        gl_lds16(xs0 + (size_t)st * 512, xb + lane * 16);
        gl_lds16(xs1 + (size_t)st * 512, xb + 1024 + lane * 16);
    };

    f32x4 acc[4];
    #pragma unroll
    for (int n = 0; n < 4; ++n) acc[n] = (f32x4){0.f, 0.f, 0.f, 0.f};

    const int rm = lane & 7;                        // (row&7), row = lane&15
    const char* xrow = smem + (lane & 15) * 2048;   // this lane's row slab
    const int ga = wid * 8 + 2 * (lane >> 4);       // logical granule base (8-aligned window)

    STAGE(0, 0);
    asm volatile("s_waitcnt vmcnt(0)" ::: "memory");
    __builtin_amdgcn_s_barrier();
    __builtin_amdgcn_sched_barrier(0);

    #pragma unroll 1
    for (int st = 0; st < NSTEP; ++st) {
        if (st + 1 < NSTEP) STAGE(st + 1, (st + 1) & 1);
        __builtin_amdgcn_sched_barrier(0);   // prefetch issued before compute

        const char* xb = xrow + (st & 1) * 32768;
        float4 xa = *reinterpret_cast<const float4*>(xb + ((ga    ) ^ rm) * 16);
        float4 xc = *reinterpret_cast<const float4*>(xb + ((ga + 1) ^ rm) * 16);
        short8 ah, al;
        split8(xa, xc, ah, al);

        // B fragments direct from L2-resident pre-split W
        const int ksl = st * 64 + wid * 4 + (lane >> 4);
        const unsigned short* bp = wsp + ((size_t)ksl * 64 + (lane & 15)) * 8;
        short8 bh[4], bl[4];
        #pragma unroll
        for (int n = 0; n < 4; ++n) {
            bh[n] = *reinterpret_cast<const short8*>(bp + n * 128);
            bl[n] = *reinterpret_cast<const short8*>(bp + WSPLIT_SHORTS + n * 128);
        }

        #pragma unroll
        for (int n = 0; n < 4; ++n)
            acc[n] = __builtin_amdgcn_mfma_f32_16x16x32_bf16(ah, bh[n], acc[n], 0, 0, 0);
        #pragma unroll
        for (int n = 0; n < 4; ++n)
            acc[n] = __builtin_amdgcn_mfma_f32_16x16x32_bf16(ah, bl[n], acc[n], 0, 0, 0);
        #pragma unroll
        for (int n = 0; n < 4; ++n)
            acc[n] = __builtin_amdgcn_mfma_f32_16x16x32_bf16(al, bh[n], acc[n], 0, 0, 0);

        // end of step: next-step DMA complete (had whole compute phase), buffers sync'd
        asm volatile("s_waitcnt vmcnt(0)" ::: "memory");
        __builtin_amdgcn_s_barrier();
        __builtin_amdgcn_sched_barrier(0);
    }

    __syncthreads();

    // ---- 16-way k-reduce via LDS ----
    float* const part = reinterpret_cast<float*>(smem);            // 15*1024 f32
    float* const Lb   = reinterpret_cast<float*>(smem + 61440);    // [64 e][17]
    float* const red  = reinterpret_cast<float*>(smem + 65792);    // 2*16*64 f32

    if (wid > 0) {
        #pragma unroll
        for (int n = 0; n < 4; ++n)
            #pragma unroll
            for (int j = 0; j < 4; ++j)
                part[(wid - 1) * 1024 + lane * 16 + n * 4 + j] = acc[n][j];
    }
    __syncthreads();
    if (wid == 0) {
        #pragma unroll
        for (int n = 0; n < 4; ++n) {
            #pragma unroll
            for (int j = 0; j < 4; ++j) {
                float v = acc[n][j];
                #pragma unroll
                for (int g = 0; g < 15; ++g)
                    v += part[g * 1024 + lane * 16 + n * 4 + j];
                // C layout (m89-verified): col = lane&15, row = (lane>>4)*4 + j
                const int e  = n * 16 + (lane & 15);
                const int rl = (lane >> 4) * 4 + j;
                Lb[e * 17 + rl] = v;
            }
        }
    }
    __syncthreads();

    // ---- softmax + top-2 (lane = expert), one row per wave (r = wid) ----
    const float blane = b[lane];
    float* outIdx = out;
    float* outVal = out + (size_t)SROWS * 2;

    const int r = wid;
    const float logit = Lb[lane * 17 + r] + blane;

    float v1 = logit; int i1 = lane;
    #pragma unroll
    for (int off = 32; off; off >>= 1) {
        float ov = __shfl_xor(v1, off);
        int   oi = __shfl_xor(i1, off);
        if (ov > v1 || (ov == v1 && oi < i1)) { v1 = ov; i1 = oi; }
    }
    float p = expf(logit - v1);
    float ssum = p;
    #pragma unroll
    for (int off = 32; off; off >>= 1) ssum += __shfl_xor(ssum, off);

    float v2 = (lane == i1) ? -3.402823466e38f : logit;
    int i2 = lane;
    #pragma unroll
    for (int off = 32; off; off >>= 1) {
        float ov = __shfl_xor(v2, off);
        int   oi = __shfl_xor(i2, off);
        if (ov > v2 || (ov == v2 && oi < i2)) { v2 = ov; i2 = oi; }
    }

    const float impAcc = p / ssum;
    const float cntAcc = (i1 == lane) ? 1.f : 0.f;

    if (lane == 0) {
        const int sr = row0 + r;
        outIdx[sr * 2 + 0] = (float)i1;
        outIdx[sr * 2 + 1] = (float)i2;
        outVal[sr * 2 + 0] = 1.f / ssum;
        outVal[sr * 2 + 1] = expf(v2 - v1) / ssum;
    }

    // ---- per-block reduce of importance / count partials ----
    __syncthreads();
    red[wid * 64 + lane]        = impAcc;
    red[1024 + wid * 64 + lane] = cntAcc;
    __syncthreads();
    if (tid < 64) {
        float si = 0.f, sc2 = 0.f;
        #pragma unroll
        for (int g = 0; g < 16; ++g) {
            si  += red[g * 64 + tid];
            sc2 += red[1024 + g * 64 + tid];
        }
        ws[WSOFF_F + (size_t)blockIdx.x * 64 + tid] = si;
        ws[WSOFF2  + (size_t)blockIdx.x * 64 + tid] = sc2;
    }
}

__global__ void gate_reduce(const float* __restrict__ ws, float* __restrict__ out)
{
    __shared__ float li[64 * 64], lc[64 * 64];     // [group][expert]
    const int t = threadIdx.x;                     // 1024 threads
    const int g  = t >> 4;                         // 0..63, 16 blocks each
    const int e4 = (t & 15) * 4;                   // expert quad
    float4 si = make_float4(0.f, 0.f, 0.f, 0.f);
    float4 sc = make_float4(0.f, 0.f, 0.f, 0.f);
    const int base = g * 16;
    #pragma unroll 4
    for (int bb = base; bb < base + 16; ++bb) {
        float4 a = *reinterpret_cast<const float4*>(&ws[WSOFF_F + (size_t)bb * 64 + e4]);
        float4 c = *reinterpret_cast<const float4*>(&ws[WSOFF2  + (size_t)bb * 64 + e4]);
        si.x += a.x; si.y += a.y; si.z += a.z; si.w += a.w;
        sc.x += c.x; sc.y += c.y; sc.z += c.z; sc.w += c.w;
    }
    *reinterpret_cast<float4*>(&li[g * 64 + e4]) = si;
    *reinterpret_cast<float4*>(&lc[g * 64 + e4]) = sc;
    __syncthreads();
    if (t < 64) {
        float ti = 0.f, tc = 0.f;
        #pragma unroll 8
        for (int gg = 0; gg < 64; ++gg) { ti += li[gg * 64 + t]; tc += lc[gg * 64 + t]; }
        li[t] = ti * tc;    // reuse row 0
    }
    __syncthreads();
    if (t == 0) {
        float s = 0.f;
        for (int i = 0; i < NE; ++i) s += li[i];
        out[(size_t)SROWS * 4] = s * ((float)NE / ((float)SROWS * (float)SROWS));
    }
}

extern "C" void kernel_launch(void* const* d_in, const int* in_sizes, int n_in,
                              void* d_out, int out_size, void* d_ws, size_t ws_size,
                              hipStream_t stream)
{
    const float* x = (const float*)d_in[0];
    const float* W = (const float*)d_in[1];
    const float* b = (const float*)d_in[2];
    float* out = (float*)d_out;
    unsigned short* wsp = (unsigned short*)d_ws;
    float* wsf = (float*)d_ws;

    hipFuncSetAttribute(reinterpret_cast<const void*>(gate_main),
                        hipFuncAttributeMaxDynamicSharedMemorySize, LDS_BYTES);

    w_split<<<128, 256, 0, stream>>>(W, wsp);
    gate_main<<<NBLK, 1024, LDS_BYTES, stream>>>(x, wsp, b, out, wsf);
    gate_reduce<<<1, 1024, 0, stream>>>(wsf, out);
}

// Round 17
// 85.175 us; speedup vs baseline: 1.6749x; 1.6749x over previous
//
#include <hip/hip_runtime.h>
#include <hip/hip_bf16.h>

#define SROWS 16384
#define DIMK  4096
#define NE    64
#define BM    16                 // rows per block
#define NBLK  (SROWS/BM)         // 1024 blocks
#define KSPL  8                  // k-split ways = waves per block
#define KSEG  (DIMK/KSPL)        // 512 k per wave
#define NSTEP 16                 // K32 chunks per wave
#define SBK   32
#define WSPLIT_SHORTS 262144     // shorts per (hi|lo) plane of pre-split W
#define WSOFF_F 262144           // f32 offset of partials region (skip 1 MB W-split)
#define WSOFF2  (WSOFF_F + NBLK*64)

typedef __attribute__((ext_vector_type(8))) short short8;
typedef __attribute__((ext_vector_type(4))) float f32x4;

// split 8 f32 -> 8 hi bf16 + 8 lo bf16 via HW cvt (RNE); f ~= hi + lo
__device__ __forceinline__ void split8(const float4 a, const float4 c, short8& hi, short8& lo) {
    float f[8] = {a.x, a.y, a.z, a.w, c.x, c.y, c.z, c.w};
    #pragma unroll
    for (int i = 0; i < 8; ++i) {
        unsigned short h = __bfloat16_as_ushort(__float2bfloat16(f[i]));
        float hf = __uint_as_float((unsigned)h << 16);
        unsigned short l = __bfloat16_as_ushort(__float2bfloat16(f[i] - hf));
        hi[i] = (short)h;
        lo[i] = (short)l;
    }
}

// pre-pass: split W into bf16 hi/lo planes in B-fragment order [k/8][e][8]
__global__ void w_split(const float* __restrict__ W, unsigned short* __restrict__ wsp)
{
    const int idx   = blockIdx.x * 256 + threadIdx.x;   // 0..32767
    const int kslot = idx & 511;
    const int e     = idx >> 9;
    const float* p = W + (size_t)e * DIMK + kslot * 8;
    float4 va = *reinterpret_cast<const float4*>(p);
    float4 vb = *reinterpret_cast<const float4*>(p + 4);
    short8 hi, lo;
    split8(va, vb, hi, lo);
    *reinterpret_cast<short8*>(wsp + (size_t)(kslot * 64 + e) * 8)                 = hi;
    *reinterpret_cast<short8*>(wsp + WSPLIT_SHORTS + (size_t)(kslot * 64 + e) * 8) = lo;
}

// async global -> LDS, 16B per lane (DMA; dst = wave-uniform base + lane*16)
__device__ __forceinline__ void gl_lds16(const void* g, void* l) {
    __builtin_amdgcn_global_load_lds(
        (const __attribute__((address_space(1))) void*)g,
        (__attribute__((address_space(3))) void*)l, 16, 0, 0);
}

__global__ __launch_bounds__(512, 6) void gate_main(
    const float* __restrict__ x, const unsigned short* __restrict__ wsp,
    const float* __restrict__ b, float* __restrict__ out, float* __restrict__ ws)
{
    __shared__ __align__(16) char smem[32768];
    // main loop: wave-private slabs: wave w at [w*4096, +4096): 2 buffers x 2 KB
    //   slab layout [16 rows][8 granules x 16B], granule XOR-swizzled by row&7
    // epilogue (sequential phases): part 7x1088 f32 (pitch 17: bank-conflict-free)
    //   then Lb[64][17] @0 after part consumed; red @8192

    const int tid  = threadIdx.x;
    const int lane = tid & 63;
    const int wid  = __builtin_amdgcn_readfirstlane(tid >> 6);  // 0..7 = k-split wave
    const int row0 = blockIdx.x * BM;

    // ---- wave-private staging: 2 instr/step, slot s=q*64+lane -> row s>>3, granule s&7 ----
    const float* xsq[2];
    #pragma unroll
    for (int q = 0; q < 2; ++q) {
        const int s = q * 64 + lane;
        const int r = s >> 3;
        const int glog = (s & 7) ^ (r & 7);     // pre-swizzled source granule
        xsq[q] = x + (size_t)(row0 + r) * DIMK + wid * KSEG + glog * 4;
    }
    char* const xslab = smem + wid * 4096;

    auto STAGE = [&](int st, int bsel) {
        char* xb = xslab + bsel * 2048;
        #pragma unroll
        for (int q = 0; q < 2; ++q)
            gl_lds16(xsq[q] + (size_t)st * SBK, xb + q * 1024 + lane * 16);
    };

    f32x4 acc[4];
    #pragma unroll
    for (int n = 0; n < 4; ++n) acc[n] = (f32x4){0.f, 0.f, 0.f, 0.f};

    const int rm = lane & 7;                        // (row&7), row = lane&15
    const char* xrow = xslab + (lane & 15) * 128;   // this lane's row (8 granules)
    const int h = lane >> 4;                        // k-slice quarter

    STAGE(0, 0);

    #pragma unroll 1
    for (int st = 0; st < NSTEP; ++st) {
        // wait own DMA(st) (issued one full step ago)
        asm volatile("s_waitcnt vmcnt(0)" ::: "memory");
        __builtin_amdgcn_sched_barrier(0);
        if (st + 1 < NSTEP) STAGE(st + 1, (st + 1) & 1);

        const char* xb = xrow + (st & 1) * 2048;
        float4 xa = *reinterpret_cast<const float4*>(xb + ((2 * h    ) ^ rm) * 16);
        float4 xc = *reinterpret_cast<const float4*>(xb + ((2 * h + 1) ^ rm) * 16);
        short8 ah, al;
        split8(xa, xc, ah, al);

        // B fragments direct from L2-resident pre-split W
        const int ksl = wid * 64 + st * 4 + h;
        const unsigned short* bp = wsp + ((size_t)ksl * 64 + (lane & 15)) * 8;
        short8 bh[4], bl[4];
        #pragma unroll
        for (int n = 0; n < 4; ++n) {
            bh[n] = *reinterpret_cast<const short8*>(bp + n * 128);
            bl[n] = *reinterpret_cast<const short8*>(bp + WSPLIT_SHORTS + n * 128);
        }

        #pragma unroll
        for (int n = 0; n < 4; ++n)
            acc[n] = __builtin_amdgcn_mfma_f32_16x16x32_bf16(ah, bh[n], acc[n], 0, 0, 0);
        #pragma unroll
        for (int n = 0; n < 4; ++n)
            acc[n] = __builtin_amdgcn_mfma_f32_16x16x32_bf16(ah, bl[n], acc[n], 0, 0, 0);
        #pragma unroll
        for (int n = 0; n < 4; ++n)
            acc[n] = __builtin_amdgcn_mfma_f32_16x16x32_bf16(al, bh[n], acc[n], 0, 0, 0);
    }

    __syncthreads();   // first block-wide sync

    // ---- 8-way k-reduce, pitch-17 partials (bank-conflict-free) ----
    float* const part = reinterpret_cast<float*>(smem);     // 7 x 1088 f32 = 30464 B

    if (wid > 0) {
        #pragma unroll
        for (int n = 0; n < 4; ++n)
            #pragma unroll
            for (int j = 0; j < 4; ++j)
                part[(wid - 1) * 1088 + lane * 17 + n * 4 + j] = acc[n][j];
    }
    __syncthreads();
    if (wid == 0) {
        #pragma unroll
        for (int n = 0; n < 4; ++n) {
            #pragma unroll
            for (int j = 0; j < 4; ++j) {
                float v = acc[n][j];
                #pragma unroll
                for (int g = 0; g < 7; ++g)
                    v += part[g * 1088 + lane * 17 + n * 4 + j];
                acc[n][j] = v;
            }
        }
    }
    __syncthreads();   // all part reads done; region reusable

    float* const Lb  = reinterpret_cast<float*>(smem);          // [64 e][17]
    float* const red = reinterpret_cast<float*>(smem + 8192);   // 2 x 512 f32

    if (wid == 0) {
        #pragma unroll
        for (int n = 0; n < 4; ++n) {
            #pragma unroll
            for (int j = 0; j < 4; ++j) {
                // C layout (m89-verified): col = lane&15, row = (lane>>4)*4 + j
                const int e  = n * 16 + (lane & 15);
                const int rl = (lane >> 4) * 4 + j;
                Lb[e * 17 + rl] = acc[n][j];
            }
        }
    }
    __syncthreads();

    // ---- softmax + top-2 per row (lane = expert), 2 rows/wave ----
    float impAcc = 0.f, cntAcc = 0.f;
    const float blane = b[lane];
    float* outIdx = out;
    float* outVal = out + (size_t)SROWS * 2;

    #pragma unroll 1
    for (int rr = 0; rr < 2; ++rr) {
        const int r = wid * 2 + rr;
        const float logit = Lb[lane * 17 + r] + blane;

        float v1 = logit; int i1 = lane;
        #pragma unroll
        for (int off = 32; off; off >>= 1) {
            float ov = __shfl_xor(v1, off);
            int   oi = __shfl_xor(i1, off);
            if (ov > v1 || (ov == v1 && oi < i1)) { v1 = ov; i1 = oi; }
        }
        float p = expf(logit - v1);
        float ssum = p;
        #pragma unroll
        for (int off = 32; off; off >>= 1) ssum += __shfl_xor(ssum, off);

        float v2 = (lane == i1) ? -3.402823466e38f : logit;
        int i2 = lane;
        #pragma unroll
        for (int off = 32; off; off >>= 1) {
            float ov = __shfl_xor(v2, off);
            int   oi = __shfl_xor(i2, off);
            if (ov > v2 || (ov == v2 && oi < i2)) { v2 = ov; i2 = oi; }
        }

        impAcc += p / ssum;
        cntAcc += (i1 == lane) ? 1.f : 0.f;

        if (lane == 0) {
            const int sr = row0 + r;
            outIdx[sr * 2 + 0] = (float)i1;
            outIdx[sr * 2 + 1] = (float)i2;
            outVal[sr * 2 + 0] = 1.f / ssum;
            outVal[sr * 2 + 1] = expf(v2 - v1) / ssum;
        }
    }

    // ---- per-block reduce of importance / count partials ----
    __syncthreads();
    red[wid * 64 + lane]       = impAcc;
    red[512 + wid * 64 + lane] = cntAcc;
    __syncthreads();
    if (tid < 64) {
        float si = 0.f, sc2 = 0.f;
        #pragma unroll
        for (int g = 0; g < KSPL; ++g) {
            si  += red[g * 64 + tid];
            sc2 += red[512 + g * 64 + tid];
        }
        ws[WSOFF_F + (size_t)blockIdx.x * 64 + tid] = si;
        ws[WSOFF2  + (size_t)blockIdx.x * 64 + tid] = sc2;
    }
}

__global__ void gate_reduce(const float* __restrict__ ws, float* __restrict__ out)
{
    __shared__ float li[64 * 64], lc[64 * 64];     // [group][expert]
    const int t = threadIdx.x;                     // 1024 threads
    const int g  = t >> 4;                         // 0..63, 16 blocks each
    const int e4 = (t & 15) * 4;                   // expert quad
    float4 si = make_float4(0.f, 0.f, 0.f, 0.f);
    float4 sc = make_float4(0.f, 0.f, 0.f, 0.f);
    const int base = g * 16;
    #pragma unroll 4
    for (int bb = base; bb < base + 16; ++bb) {
        float4 a = *reinterpret_cast<const float4*>(&ws[WSOFF_F + (size_t)bb * 64 + e4]);
        float4 c = *reinterpret_cast<const float4*>(&ws[WSOFF2  + (size_t)bb * 64 + e4]);
        si.x += a.x; si.y += a.y; si.z += a.z; si.w += a.w;
        sc.x += c.x; sc.y += c.y; sc.z += c.z; sc.w += c.w;
    }
    *reinterpret_cast<float4*>(&li[g * 64 + e4]) = si;
    *reinterpret_cast<float4*>(&lc[g * 64 + e4]) = sc;
    __syncthreads();
    if (t < 64) {
        float ti = 0.f, tc = 0.f;
        #pragma unroll 8
        for (int gg = 0; gg < 64; ++gg) { ti += li[gg * 64 + t]; tc += lc[gg * 64 + t]; }
        li[t] = ti * tc;    // reuse row 0
    }
    __syncthreads();
    if (t == 0) {
        float s = 0.f;
        for (int i = 0; i < NE; ++i) s += li[i];
        out[(size_t)SROWS * 4] = s * ((float)NE / ((float)SROWS * (float)SROWS));
    }
}

extern "C" void kernel_launch(void* const* d_in, const int* in_sizes, int n_in,
                              void* d_out, int out_size, void* d_ws, size_t ws_size,
                              hipStream_t stream)
{
    const float* x = (const float*)d_in[0];
    const float* W = (const float*)d_in[1];
    const float* b = (const float*)d_in[2];
    float* out = (float*)d_out;
    unsigned short* wsp = (unsigned short*)d_ws;
    float* wsf = (float*)d_ws;

    w_split<<<128, 256, 0, stream>>>(W, wsp);
    gate_main<<<NBLK, 512, 0, stream>>>(x, wsp, b, out, wsf);
    gate_reduce<<<1, 1024, 0, stream>>>(wsf, out);
}